// Round 14
// baseline (1368.046 us; speedup 1.0000x reference)
//
#include <hip/hip_runtime.h>
#include <math.h>

#define TT 256
#define HH 100
#define GG 400
#define BB 512

typedef float  f32x4  __attribute__((ext_vector_type(4)));
typedef short  bf16x8 __attribute__((ext_vector_type(8)));

// raw transcendental ops (validated: absmax 6.1e-5 in R8-R13)
__device__ __forceinline__ float fexp2(float x) {
    float r; asm("v_exp_f32 %0, %1" : "=v"(r) : "v"(x)); return r;
}
__device__ __forceinline__ float frcp(float x) {
    float r; asm("v_rcp_f32 %0, %1" : "=v"(r) : "v"(x)); return r;
}
#define LOG2E 1.44269504088896f

// bf16 round-to-nearest-even of fp32 (returns 16-bit pattern)
__device__ __forceinline__ unsigned bf16rne(float x) {
    unsigned b = __float_as_uint(x);
    return (b + 0x7FFFu + ((b >> 16) & 1u)) >> 16;
}

// LDS-drain-only barrier: keeps global loads/stores in flight
__device__ __forceinline__ void bar_lds() {
    asm volatile("s_waitcnt lgkmcnt(0)" ::: "memory");
    __builtin_amdgcn_s_barrier();
    asm volatile("" ::: "memory");
}

// ============================ recurrence kernel ==============================
// MFMA bf16x3 recurrence: pre[2][400] = h[2][100] @ W_hh^T via
// mfma_f32_16x16x32_bf16, W split hi/lo bf16 resident in VGPR/AGPR fragments
// (MFMA reads AGPRs natively -> the AGPR-banking that taxed R4-R13's vector
// FMA designs 2x is free here).
// 256 blocks x 512 threads (8 waves), 2 batch rows/block (M rows 0-1 of 16).
// Wave w owns N-tiles 4w+q (16 gates each), q=0..3, valid while 4w+q<25.
// K=100 padded to 128 (4 K-tiles of 32; pads zero).
// Fragments (verified/derived layouts):
//   A (16x32): lane l: row=l&15, k=8*(l>>4)+e  (contiguous 8 bf16 = b128)
//   B (32x16): lane l: col=l&15, k=8*(l>>4)+e ; B=W^T so lane holds W[g][k..k+7]
//   C/D: col=lane&15, row=(lane>>4)*4+reg [m89] -> rows 0,1 in lanes 0-15 regs 0,1
// h kept in LDS pre-split: hb[buf][row][hi/lo][128] bf16 -> A-prep is 8 masked
// ds_read_b128 per wave per step, zero VALU.
template<int LK>
__global__ void __launch_bounds__(512, 2)
lstm_recur(const float* __restrict__ x,        // [B][T][2]   (LK==0)
           const float* __restrict__ pre,      // [T*B][400]  (LK>=1, bias folded)
           const float* __restrict__ Whh,      // [400][100]
           const float* __restrict__ Wih0,     // [400][2]    (LK==0)
           const float* __restrict__ bih,      // [400]       (LK==0)
           const float* __restrict__ bhh,      // [400]       (LK==0)
           const float* __restrict__ head_w,   // [100]
           const float* __restrict__ head_b,   // [1]
           float* __restrict__ hs,             // [B][T][100] (LK<2 out)
           float* __restrict__ out)            // [B]         (LK==2 out)
{
    __shared__ __align__(16) short hb[2][2][2][128]; // [buf][row][hi/lo][k]
    __shared__ float gbuf[2][400];                   // raw MFMA pre-activations
    __shared__ float hfin[2][100];                   // fp32 h for head (LK2)

    const int tid = threadIdx.x;
    const int b0  = blockIdx.x * 2;
    const int l   = tid & 63;          // lane
    const int w   = tid >> 6;          // wave 0..7
    const int lr  = l & 15;            // fragment row/col
    const int lg  = l >> 4;            // k-group

    // ---- build W fragments (once): wave w, tiles n=4w+q, K-tiles kt ----
    bf16x8 Bhi[4][4], Blo[4][4];
    #pragma unroll
    for (int q = 0; q < 4; ++q) {
        #pragma unroll
        for (int kt = 0; kt < 4; ++kt) {
            const int n  = 4 * w + q;
            const int g  = 16 * n + lr;
            const int k0 = 32 * kt + 8 * lg;
            float4 v0 = {0.f, 0.f, 0.f, 0.f}, v1 = {0.f, 0.f, 0.f, 0.f};
            if (n < 25) {
                const float* wr = Whh + (size_t)g * HH;
                if (k0     <= 96) v0 = *(const float4*)(wr + k0);
                if (k0 + 4 <= 96) v1 = *(const float4*)(wr + k0 + 4);
            }
            const float e[8] = {v0.x, v0.y, v0.z, v0.w, v1.x, v1.y, v1.z, v1.w};
            short sh[8], sl[8];
            #pragma unroll
            for (int i = 0; i < 8; ++i) {
                const unsigned hh = bf16rne(e[i]);
                const float rem = e[i] - __uint_as_float(hh << 16);
                sh[i] = (short)hh;
                sl[i] = (short)bf16rne(rem);
            }
            Bhi[q][kt] = (bf16x8){sh[0],sh[1],sh[2],sh[3],sh[4],sh[5],sh[6],sh[7]};
            Blo[q][kt] = (bf16x8){sl[0],sl[1],sl[2],sl[3],sl[4],sl[5],sl[6],sl[7]};
        }
    }

    // ---- update-thread setup (tid<200): r=row, u=unit ----
    const int r = (tid < 200) ? (tid / 100) : 0;
    const int u = (tid < 200) ? (tid - (tid / 100) * 100) : 0;
    float biasv[4] = {0,0,0,0}, wav[4] = {0,0,0,0}, wbv[4] = {0,0,0,0};
    float p4[4] = {0,0,0,0};
    float2 xv = {0.f, 0.f};
    float c = 0.f;
    if (tid < 200) {
        if (LK == 0) {
            #pragma unroll
            for (int d = 0; d < 4; ++d) {
                const int g = d * 100 + u;
                biasv[d] = bih[g] + bhh[g];
                wav[d] = Wih0[2 * g]; wbv[d] = Wih0[2 * g + 1];
            }
            xv = *(const float2*)(x + ((size_t)(b0 + r) * TT + 0) * 2);
        } else {
            #pragma unroll
            for (int d = 0; d < 4; ++d)
                p4[d] = pre[((size_t)0 * BB + b0 + r) * GG + d * 100 + u];
        }
    }

    // ---- zero hb (both buffers, incl. k=100..127 pads) ----
    {
        short* hp = &hb[0][0][0][0];
        #pragma unroll
        for (int i = 0; i < 2; ++i) hp[tid + 512 * i] = 0;   // 1024 shorts
        hp[tid + 1024] = 0;                                   // wait: 2048 total
        hp[tid + 1536] = 0;
    }
    __syncthreads();

    // ============================ time loop ============================
    for (int t = 0; t < TT; ++t) {
        const int cur = t & 1;

        // ---- A-prep: masked b128 loads of pre-split h ----
        bf16x8 Ahi[4], Alo[4];
        #pragma unroll
        for (int kt = 0; kt < 4; ++kt) {
            Ahi[kt] = (bf16x8){0,0,0,0,0,0,0,0};
            Alo[kt] = (bf16x8){0,0,0,0,0,0,0,0};
        }
        if (lr < 2) {
            #pragma unroll
            for (int kt = 0; kt < 4; ++kt) {
                const int k0 = 32 * kt + 8 * lg;
                Ahi[kt] = *(const bf16x8*)&hb[cur][lr][0][k0];
                Alo[kt] = *(const bf16x8*)&hb[cur][lr][1][k0];
            }
        }

        // ---- MFMA: acc[q] = sum_kt (Ahi*Bhi + Alo*Bhi + Ahi*Blo) ----
        #pragma unroll
        for (int q = 0; q < 4; ++q) {
            if (4 * w + q < 25) {
                f32x4 acc = {0.f, 0.f, 0.f, 0.f};
                #pragma unroll
                for (int kt = 0; kt < 4; ++kt) {
                    acc = __builtin_amdgcn_mfma_f32_16x16x32_bf16(Ahi[kt], Bhi[q][kt], acc, 0, 0, 0);
                    acc = __builtin_amdgcn_mfma_f32_16x16x32_bf16(Alo[kt], Bhi[q][kt], acc, 0, 0, 0);
                    acc = __builtin_amdgcn_mfma_f32_16x16x32_bf16(Ahi[kt], Blo[q][kt], acc, 0, 0, 0);
                }
                if ((l & 48) == 0) {            // lanes 0-15: rows 0,1 in regs 0,1
                    gbuf[0][16 * (4 * w + q) + lr] = acc[0];
                    gbuf[1][16 * (4 * w + q) + lr] = acc[1];
                }
            }
        }
        bar_lds();   // gbuf complete; hb[cur] reads done

        // ---- gate update (200 threads: row r, unit u) ----
        if (tid < 200) {
            float pr[4];
            pr[0] = gbuf[r][u];       pr[1] = gbuf[r][100 + u];
            pr[2] = gbuf[r][200 + u]; pr[3] = gbuf[r][300 + u];
            const int tn = (t + 1 < TT) ? t + 1 : t;
            if (LK == 0) {
                #pragma unroll
                for (int d = 0; d < 4; ++d)
                    pr[d] += biasv[d] + wav[d] * xv.x + wbv[d] * xv.y;
                xv = *(const float2*)(x + ((size_t)(b0 + r) * TT + tn) * 2);
            } else {
                #pragma unroll
                for (int d = 0; d < 4; ++d) pr[d] += p4[d];
                #pragma unroll
                for (int d = 0; d < 4; ++d)
                    p4[d] = pre[((size_t)tn * BB + b0 + r) * GG + d * 100 + u];
            }
            const float si = frcp(1.f + fexp2(-LOG2E * pr[0]));
            const float sf = frcp(1.f + fexp2(-LOG2E * pr[1]));
            const float tg = 2.f * frcp(1.f + fexp2(-2.f * LOG2E * pr[2])) - 1.f;
            const float so = frcp(1.f + fexp2(-LOG2E * pr[3]));
            c = sf * c + si * tg;
            const float th = 2.f * frcp(1.f + fexp2(-2.f * LOG2E * c)) - 1.f;
            const float hv = so * th;
            // split h -> bf16 hi/lo for next step's A operands
            const unsigned hh = bf16rne(hv);
            const float rem = hv - __uint_as_float(hh << 16);
            const unsigned hl = bf16rne(rem);
            const int nb = cur ^ 1;
            hb[nb][r][0][u] = (short)hh;
            hb[nb][r][1][u] = (short)hl;
            if (LK == 2) hfin[r][u] = hv;
            if (LK < 2) hs[((size_t)(b0 + r) * TT + t) * HH + u] = hv;
        }
        bar_lds();   // hb[nxt] visible; gbuf consumed
    }

    // ---- head (LK2): out[b] = dot(h_last, head_w) + head_b ----
    if (LK == 2 && tid < 128) {
        const int lane = tid & 63, wv = tid >> 6;
        float p = hfin[wv][lane] * head_w[lane];
        if (lane < 36) p += hfin[wv][64 + lane] * head_w[64 + lane];
        #pragma unroll
        for (int off = 32; off; off >>= 1) p += __shfl_down(p, off);
        if (lane == 0) out[b0 + wv] = p + head_b[0];
    }
}

// ============================ x-projection GEMM ==============================
// (unchanged from R11 — ~135 us each) 8x8-fragment tiled GEMM, LDS-BW bound.
__global__ void __launch_bounds__(400, 1)
gemm_pre(const float* __restrict__ hs,     // [B][T][100]
         const float* __restrict__ Wih,    // [400][100]
         const float* __restrict__ bih,    // [400]
         const float* __restrict__ bhh,    // [400]
         float* __restrict__ pre)          // [M][400]
{
    extern __shared__ float lds[];
    float* A_s = lds;            // [100][128]  12800 floats
    float* W_s = lds + 12800;    // [100][200]  20000 floats

    const int tid = threadIdx.x;           // 400
    const int ti  = tid / 25;              // 0..15 -> rows 8ti..8ti+7
    const int tj  = tid % 25;              // 0..24 -> gates 8tj..8tj+7
    const int row0   = blockIdx.x * 128;   // same t (512%128==0)
    const int t      = row0 >> 9;
    const int b_base = row0 & 511;
    const int gbase  = blockIdx.y * 200;

    #pragma unroll
    for (int s = 0; s < 8; ++s) {
        const int L  = tid + 400 * s;      // 0..3199
        const int r  = L / 25, kq = L % 25;
        float4 v = *(const float4*)(hs + ((size_t)(b_base + r) * TT + t) * HH + 4 * kq);
        const int ph = r ^ ((kq & 7) << 3);
        A_s[(4*kq+0)*128 + ph] = v.x;
        A_s[(4*kq+1)*128 + ph] = v.y;
        A_s[(4*kq+2)*128 + ph] = v.z;
        A_s[(4*kq+3)*128 + ph] = v.w;
    }
    for (int L = tid; L < 5000; L += 400) {
        const int kq = L / 200, gl = L % 200;
        float4 v = *(const float4*)(Wih + (size_t)(gbase + gl) * HH + 4 * kq);
        W_s[(4*kq+0)*200 + gl] = v.x;
        W_s[(4*kq+1)*200 + gl] = v.y;
        W_s[(4*kq+2)*200 + gl] = v.z;
        W_s[(4*kq+3)*200 + gl] = v.w;
    }
    __syncthreads();

    float bj[8];
    {
        const float4 a1 = *(const float4*)(bih + gbase + 8 * tj);
        const float4 a2 = *(const float4*)(bih + gbase + 8 * tj + 4);
        const float4 c1 = *(const float4*)(bhh + gbase + 8 * tj);
        const float4 c2 = *(const float4*)(bhh + gbase + 8 * tj + 4);
        bj[0] = a1.x + c1.x; bj[1] = a1.y + c1.y; bj[2] = a1.z + c1.z; bj[3] = a1.w + c1.w;
        bj[4] = a2.x + c2.x; bj[5] = a2.y + c2.y; bj[6] = a2.z + c2.z; bj[7] = a2.w + c2.w;
    }
    float acc[8][8];
    #pragma unroll
    for (int i = 0; i < 8; ++i)
        #pragma unroll
        for (int j = 0; j < 8; ++j) acc[i][j] = bj[j];

    for (int kq = 0; kq < 25; ++kq) {
        const int axo = (8 * ti) ^ ((kq & 7) << 3);
        #pragma unroll
        for (int e = 0; e < 4; ++e) {
            const float* Ak = &A_s[(4*kq + e) * 128];
            const float* Wk = &W_s[(4*kq + e) * 200];
            const float4 a0 = *(const float4*)(Ak + axo);
            const float4 a1 = *(const float4*)(Ak + axo + 4);
            const float4 w0 = *(const float4*)(Wk + 8 * tj);
            const float4 w1 = *(const float4*)(Wk + 8 * tj + 4);
            const float av[8] = {a0.x, a0.y, a0.z, a0.w, a1.x, a1.y, a1.z, a1.w};
            const float wv[8] = {w0.x, w0.y, w0.z, w0.w, w1.x, w1.y, w1.z, w1.w};
            #pragma unroll
            for (int i = 0; i < 8; ++i)
                #pragma unroll
                for (int j = 0; j < 8; ++j)
                    acc[i][j] += av[i] * wv[j];
        }
    }

    #pragma unroll
    for (int i = 0; i < 8; ++i) {
        const size_t row = (size_t)row0 + 8 * ti + i;
        float4 o0, o1;
        o0.x = acc[i][0]; o0.y = acc[i][1]; o0.z = acc[i][2]; o0.w = acc[i][3];
        o1.x = acc[i][4]; o1.y = acc[i][5]; o1.z = acc[i][6]; o1.w = acc[i][7];
        *(float4*)(pre + row * GG + gbase + 8 * tj)     = o0;
        *(float4*)(pre + row * GG + gbase + 8 * tj + 4) = o1;
    }
}

// =============================================================================
extern "C" void kernel_launch(void* const* d_in, const int* in_sizes, int n_in,
                              void* d_out, int out_size, void* d_ws, size_t ws_size,
                              hipStream_t stream) {
    const float* x         = (const float*)d_in[0];
    const float* W_ih0     = (const float*)d_in[1];
    const float* W_ih_rest = (const float*)d_in[2];
    const float* W_hh      = (const float*)d_in[3];
    const float* b_ih      = (const float*)d_in[4];
    const float* b_hh      = (const float*)d_in[5];
    const float* head_w    = (const float*)d_in[6];
    const float* head_b    = (const float*)d_in[7];
    float* out = (float*)d_out;

    const size_t HS_BYTES = (size_t)BB * TT * HH * 4;   // 52.4 MB
    float* hs  = (float*)d_ws;
    float* pre = (float*)((char*)d_ws + HS_BYTES);      // 209.7 MB

    const int gemm_lds = (12800 + 20000) * 4;           // 131,200 B
    hipFuncSetAttribute((const void*)gemm_pre,
                        hipFuncAttributeMaxDynamicSharedMemorySize, gemm_lds);
    dim3 ggrid(1024, 2);

    lstm_recur<0><<<256, 512, 0, stream>>>(
        x, nullptr, W_hh, W_ih0, b_ih, b_hh, head_w, head_b, hs, out);

    gemm_pre<<<ggrid, 400, gemm_lds, stream>>>(hs, W_ih_rest, b_ih + GG, b_hh + GG, pre);
    lstm_recur<1><<<256, 512, 0, stream>>>(
        nullptr, pre, W_hh + 40000, nullptr, nullptr, nullptr, head_w, head_b, hs, out);

    gemm_pre<<<ggrid, 400, gemm_lds, stream>>>(hs, W_ih_rest + 40000, b_ih + 2*GG, b_hh + 2*GG, pre);
    lstm_recur<2><<<256, 512, 0, stream>>>(
        nullptr, pre, W_hh + 80000, nullptr, nullptr, nullptr, head_w, head_b, hs, out);
}

// Round 15
// 996.155 us; speedup vs baseline: 1.3733x; 1.3733x over previous
//
#include <hip/hip_runtime.h>
#include <math.h>

#define TT 256
#define HH 100
#define GG 400
#define BB 512

typedef float  f32x4  __attribute__((ext_vector_type(4)));
typedef short  bf16x8 __attribute__((ext_vector_type(8)));

// ---- DPP quad-perm helpers (4-lane groups; VALU pipe) ----------------------
#define DPP_ROT1 147   // dest l <- src (l-1)&3 : perm [3,0,1,2]
#define DPP_ROT2 78    // dest l <- src (l-2)&3 : perm [2,3,0,1]
#define DPP_ROT3 57    // dest l <- src (l-3)&3 : perm [1,2,3,0]
#define DPP_XOR1 177   // perm [1,0,3,2]
#define DPP_XOR2 78    // perm [2,3,0,1]
#define DPP_XOR3 27    // perm [3,2,1,0]

template<int CTRL>
__device__ __forceinline__ float dppf(float v) {
    int i = __float_as_int(v);
    int r = __builtin_amdgcn_update_dpp(i, i, CTRL, 0xf, 0xf, false);
    return __int_as_float(r);
}

// raw transcendental ops (validated: absmax 6.1e-5 since R8)
__device__ __forceinline__ float fexp2(float x) {
    float r; asm("v_exp_f32 %0, %1" : "=v"(r) : "v"(x)); return r;
}
__device__ __forceinline__ float frcp(float x) {
    float r; asm("v_rcp_f32 %0, %1" : "=v"(r) : "v"(x)); return r;
}
#define LOG2E 1.44269504088896f

// bf16 round-to-nearest-even of fp32 (returns 16-bit pattern)
__device__ __forceinline__ unsigned bf16rne(float x) {
    unsigned b = __float_as_uint(x);
    return (b + 0x7FFFu + ((b >> 16) & 1u)) >> 16;
}

// LDS-drain-only barrier: keeps global loads/stores in flight
__device__ __forceinline__ void bar_lds() {
    asm volatile("s_waitcnt lgkmcnt(0)" ::: "memory");
    __builtin_amdgcn_s_barrier();
    asm volatile("" ::: "memory");
}

// ============================ recurrence kernel ==============================
// R8/R11 structure (best measured vector design): 512 blocks x 448 threads,
// 1 batch row/block, 2 blocks/CU; lb(448,3). Thread (u=tid>>2, ty=tid&3):
// k-quarter [25ty,25ty+25) partials for gates {((ty+d)&3)*100+u};
// DPP-rotate combine (R4-verified). h double-buffered in LDS [2][4][28].
template<int LK>
__global__ void __launch_bounds__(448, 3)
lstm_recur(const float* __restrict__ x,        // [B][T][2]   (LK==0)
           const float* __restrict__ pre,      // [T*B][400]  (LK>=1, bias folded)
           const float* __restrict__ Whh,      // [400][100]
           const float* __restrict__ Wih0,     // [400][2]    (LK==0)
           const float* __restrict__ bih,      // [400]       (LK==0)
           const float* __restrict__ bhh,      // [400]       (LK==0)
           const float* __restrict__ head_w,   // [100]
           const float* __restrict__ head_b,   // [1]
           float* __restrict__ hs,             // [B][T][100] (LK<2 out)
           float* __restrict__ out)            // [B]         (LK==2 out)
{
    __shared__ float hbuf[2][4][28];   // [buf][quarter][25 used + 3 pad]

    const int tid = threadIdx.x;
    const int b   = blockIdx.x;        // one batch row per block
    const int u   = tid >> 2, ty = tid & 3;
    const int g   = ty * HH + u;       // own gate row
    const bool on = (tid < GG);

    // Wq[d][k] = Whh[((ty+d)&3)*100 + u][25*ty + k]
    float Wq[4][25];
    float w0a = 0.f, w0b = 0.f, bias = 0.f;
    if (on) {
        #pragma unroll
        for (int d = 0; d < 4; ++d) {
            const float* wrow = Whh + (((ty + d) & 3) * HH + u) * HH + 25 * ty;
            #pragma unroll
            for (int k = 0; k < 25; ++k) Wq[d][k] = wrow[k];
        }
        if (LK == 0) {
            w0a = Wih0[2 * g]; w0b = Wih0[2 * g + 1];
            bias = bih[g] + bhh[g];
        }
    }
    if (tid < 224) (&hbuf[0][0][0])[tid] = 0.f;   // zero both bufs incl. pads
    float c = 0.f;                                // ty==0 lanes own unit u's cell
    const int q_w = u / 25, i_w = u % 25;         // writer position
    __syncthreads();

    // prefetch t=0 input
    float p0 = 0.f;
    float2 xa = {0.f, 0.f};
    if (on) {
        if (LK == 0) xa = *(const float2*)(x + (size_t)b * TT * 2);
        else         p0 = pre[((size_t)0 * BB + b) * GG + g];
    }

    for (int t = 0; t < TT; ++t) {
        const int cur = t & 1, nxt = cur ^ 1;
        if (on) {
            float ext;
            if (LK == 0) ext = bias + w0a * xa.x + w0b * xa.y;
            else         ext = p0;

            // prefetch t+1 (stays in flight across the raw barrier)
            const int tn = (t + 1 < TT) ? t + 1 : t;
            if (LK == 0) xa = *(const float2*)(x + ((size_t)b * TT + tn) * 2);
            else         p0 = pre[((size_t)tn * BB + b) * GG + g];

            const float4* hq = (const float4*)&hbuf[cur][ty][0];

            float pA = 0.f, pB = 0.f, pC = 0.f, pD = 0.f;
            #pragma unroll
            for (int i = 0; i < 6; ++i) {
                const float4 h4 = hq[i];
                pA += Wq[0][4*i+0] * h4.x; pB += Wq[1][4*i+0] * h4.x;
                pC += Wq[2][4*i+0] * h4.x; pD += Wq[3][4*i+0] * h4.x;
                pA += Wq[0][4*i+1] * h4.y; pB += Wq[1][4*i+1] * h4.y;
                pC += Wq[2][4*i+1] * h4.y; pD += Wq[3][4*i+1] * h4.y;
                pA += Wq[0][4*i+2] * h4.z; pB += Wq[1][4*i+2] * h4.z;
                pC += Wq[2][4*i+2] * h4.z; pD += Wq[3][4*i+2] * h4.z;
                pA += Wq[0][4*i+3] * h4.w; pB += Wq[1][4*i+3] * h4.w;
                pC += Wq[2][4*i+3] * h4.w; pD += Wq[3][4*i+3] * h4.w;
            }
            const float hl = hq[6].x;   // k = 24 of the quarter
            pA += Wq[0][24] * hl; pB += Wq[1][24] * hl;
            pC += Wq[2][24] * hl; pD += Wq[3][24] * hl;

            // cross-quad combine: lane j gets gate-j partials from j-1,j-2,j-3
            float tot = pA + dppf<DPP_ROT1>(pB) + dppf<DPP_ROT2>(pC)
                           + dppf<DPP_ROT3>(pD) + ext;

            // activation by own role (ty==2 is the g-gate -> tanh)
            const bool isG = (ty == 2);
            float v = isG ? 2.f * tot : tot;
            float s = frcp(1.f + fexp2(-LOG2E * v));
            if (isG) s = 2.f * s - 1.f;

            // gather the other three activated gates
            float B0 = dppf<DPP_XOR1>(s), C0 = dppf<DPP_XOR2>(s), D0 = dppf<DPP_XOR3>(s);

            if (ty == 0) {   // s=sig(i), B0=sig(f), C0=tanh(g), D0=sig(o)
                c = B0 * c + s * C0;
                float th = 2.f * frcp(1.f + fexp2(-2.f * LOG2E * c)) - 1.f;
                float hv = D0 * th;
                hbuf[nxt][q_w][i_w] = hv;
                if (LK < 2) hs[((size_t)b * TT + t) * HH + u] = hv;
            }
        }
        bar_lds();   // h(t) visible; orders hbuf[cur] reuse at t+1
    }

    // head: final h is in hbuf[0] (t=255 wrote nxt=0)
    if (LK == 2 && tid < 64) {
        const int lane = tid;
        float p = hbuf[0][lane / 25][lane % 25] * head_w[lane];
        if (lane < 36) {
            const int k2 = 64 + lane;
            p += hbuf[0][k2 / 25][k2 % 25] * head_w[k2];
        }
        #pragma unroll
        for (int off = 32; off; off >>= 1) p += __shfl_down(p, off);
        if (lane == 0) out[b] = p + head_b[0];
    }
}

// ============================ x-projection GEMM (MFMA) =======================
// pre[row][g] = bias[g] + dot(hs_row, Wih[g]) via mfma_f32_16x16x32_bf16 with
// bf16 hi/lo 3-term split (layouts+precision verified by R14: absmax 6.1e-5).
// Block: 128 rows x 200 gates, 512 threads (8 waves), grid (1024, 2).
// Wave w owns M-tile w (rows 16w..16w+15); A-frags (hi/lo) built in REGISTERS
// from global (no A LDS). W staged in LDS split hi/lo bf16 [2][208][128]
// shorts (106.5 KB), 16B-slot XOR swizzle slot^=(g&15) -> conflict-free-ish.
// Fragments (R14-verified):
//   A: lane l -> row=l&15, k=8*(l>>4)+e (contiguous b128)
//   B: lane l -> col(gate)=l&15, k=8*(l>>4)+e
//   D: col=l&15, row=(l>>4)*4+reg
__global__ void __launch_bounds__(512, 1)
gemm_pre(const float* __restrict__ hs,     // [B][T][100]
         const float* __restrict__ Wih,    // [400][100]
         const float* __restrict__ bih,    // [400]
         const float* __restrict__ bhh,    // [400]
         float* __restrict__ pre)          // [T*B][400]
{
    extern __shared__ short Ws[];          // [2][208][128] shorts (hi, lo)

    const int tid = threadIdx.x;
    const int l   = tid & 63, w = tid >> 6;   // lane, wave(=M-tile)
    const int lr  = l & 15, lg = l >> 4;
    const int row0   = blockIdx.x * 128;      // same t (512%128==0)
    const int t      = row0 >> 9;
    const int b_base = row0 & 511;
    const int gbase  = blockIdx.y * 200;

    // ---- zero W LDS (covers k>=100 and gate rows 200-207 pads) ----
    {
        int* wz = (int*)Ws;
        for (int i = tid; i < 26624; i += 512) wz[i] = 0;
    }
    __syncthreads();

    // ---- stage + split W: 200 gates x 100 k ----
    for (int L = tid; L < 20000; L += 512) {
        const int g = L / 100, k = L % 100;
        const float v = Wih[(size_t)(gbase + g) * HH + k];
        const unsigned hh = bf16rne(v);
        const float rem = v - __uint_as_float(hh << 16);
        const unsigned lo = bf16rne(rem);
        const int kp = (((k >> 3) ^ (g & 15)) << 3) | (k & 7);   // slot swizzle
        Ws[(size_t)g * 128 + kp]          = (short)hh;
        Ws[(size_t)(208 + g) * 128 + kp]  = (short)lo;
    }

    // ---- A-frags in registers: rows b_base+16w+lr, k chunks 8*lg within kt ----
    bf16x8 Ahi[4], Alo[4];
    {
        const float* hrow = hs + ((size_t)(b_base + 16 * w + lr) * TT + t) * HH;
        #pragma unroll
        for (int kt = 0; kt < 4; ++kt) {
            const int k0 = 32 * kt + 8 * lg;
            float4 v0 = {0.f,0.f,0.f,0.f}, v1 = {0.f,0.f,0.f,0.f};
            if (k0     <= 96) v0 = *(const float4*)(hrow + k0);
            if (k0 + 4 <= 96) v1 = *(const float4*)(hrow + k0 + 4);
            const float e[8] = {v0.x,v0.y,v0.z,v0.w,v1.x,v1.y,v1.z,v1.w};
            short sh[8], sl[8];
            #pragma unroll
            for (int i = 0; i < 8; ++i) {
                const unsigned hh = bf16rne(e[i]);
                const float rem = e[i] - __uint_as_float(hh << 16);
                sh[i] = (short)hh;
                sl[i] = (short)bf16rne(rem);
            }
            Ahi[kt] = (bf16x8){sh[0],sh[1],sh[2],sh[3],sh[4],sh[5],sh[6],sh[7]};
            Alo[kt] = (bf16x8){sl[0],sl[1],sl[2],sl[3],sl[4],sl[5],sl[6],sl[7]};
        }
    }
    __syncthreads();   // W staged

    // ---- N-tile loop: 13 tiles of 16 gates (tile 12 half-pad) ----
    #pragma unroll
    for (int n = 0; n < 13; ++n) {
        const int gp = 16 * n + lr;               // W row in this block's slice
        bf16x8 Bhi[4], Blo[4];
        #pragma unroll
        for (int kt = 0; kt < 4; ++kt) {
            const int slot = (4 * kt + lg) ^ (gp & 15);
            Bhi[kt] = *(const bf16x8*)&Ws[(size_t)gp * 128 + slot * 8];
            Blo[kt] = *(const bf16x8*)&Ws[(size_t)(208 + gp) * 128 + slot * 8];
        }
        f32x4 acc = {0.f, 0.f, 0.f, 0.f};
        #pragma unroll
        for (int kt = 0; kt < 4; ++kt) {
            acc = __builtin_amdgcn_mfma_f32_16x16x32_bf16(Ahi[kt], Bhi[kt], acc, 0, 0, 0);
            acc = __builtin_amdgcn_mfma_f32_16x16x32_bf16(Alo[kt], Bhi[kt], acc, 0, 0, 0);
            acc = __builtin_amdgcn_mfma_f32_16x16x32_bf16(Ahi[kt], Blo[kt], acc, 0, 0, 0);
        }
        const int gcol = gbase + 16 * n + lr;
        if (gcol < GG) {
            const float bsum = bih[gcol] + bhh[gcol];
            #pragma unroll
            for (int r = 0; r < 4; ++r) {
                const size_t row = (size_t)row0 + 16 * w + 4 * lg + r;
                pre[row * GG + gcol] = acc[r] + bsum;
            }
        }
    }
}

// =============================================================================
extern "C" void kernel_launch(void* const* d_in, const int* in_sizes, int n_in,
                              void* d_out, int out_size, void* d_ws, size_t ws_size,
                              hipStream_t stream) {
    const float* x         = (const float*)d_in[0];
    const float* W_ih0     = (const float*)d_in[1];
    const float* W_ih_rest = (const float*)d_in[2];
    const float* W_hh      = (const float*)d_in[3];
    const float* b_ih      = (const float*)d_in[4];
    const float* b_hh      = (const float*)d_in[5];
    const float* head_w    = (const float*)d_in[6];
    const float* head_b    = (const float*)d_in[7];
    float* out = (float*)d_out;

    const size_t HS_BYTES = (size_t)BB * TT * HH * 4;   // 52.4 MB
    float* hs  = (float*)d_ws;
    float* pre = (float*)((char*)d_ws + HS_BYTES);      // 209.7 MB

    const int gemm_lds = 2 * 208 * 128 * 2;             // 106,496 B
    hipFuncSetAttribute((const void*)gemm_pre,
                        hipFuncAttributeMaxDynamicSharedMemorySize, gemm_lds);
    dim3 ggrid(1024, 2);

    lstm_recur<0><<<512, 448, 0, stream>>>(
        x, nullptr, W_hh, W_ih0, b_ih, b_hh, head_w, head_b, hs, out);

    gemm_pre<<<ggrid, 512, gemm_lds, stream>>>(hs, W_ih_rest, b_ih + GG, b_hh + GG, pre);
    lstm_recur<1><<<512, 448, 0, stream>>>(
        nullptr, pre, W_hh + 40000, nullptr, nullptr, nullptr, head_w, head_b, hs, out);

    gemm_pre<<<ggrid, 512, gemm_lds, stream>>>(hs, W_ih_rest + 40000, b_ih + 2*GG, b_hh + 2*GG, pre);
    lstm_recur<2><<<512, 448, 0, stream>>>(
        nullptr, pre, W_hh + 80000, nullptr, nullptr, nullptr, head_w, head_b, hs, out);
}